// Round 7
// baseline (279.040 us; speedup 1.0000x reference)
//
#include <hip/hip_runtime.h>

// ---------------------------------------------------------------------------
// TripletContrastiveLoss on MI355X (gfx950)  — Round 7
// Base: R4 (verified-passing). Exactly one structural experiment:
//   * tile_mindist: LDS-free register GEMM (fragments loaded directly from
//     global as 16x64B fully-used sectors; no LDS, no K-loop barriers),
//     keeping R4's validated persistent-grid mapping.
// Plus one low-risk change:
//   * normalize: 16 rows/block => one atomicAdd pair per block (1024 RMWs
//     total vs 16384) — attacks the ~166 µs constant non-tile overhead.
// ws layout byte-identical to R4 (<= 16,908,304 B validated footprint).
// ---------------------------------------------------------------------------

#define B_ROWS 8192
#define DIM    1024

typedef __bf16 bf16x8 __attribute__((ext_vector_type(8)));
typedef float  f32x4  __attribute__((ext_vector_type(4)));

__device__ __forceinline__ unsigned short f2bf_rne(float x) {
    unsigned u = __float_as_uint(x);
    unsigned r = (u + 0x7FFFu + ((u >> 16) & 1u)) >> 16;
    return (unsigned short)r;
}
__device__ __forceinline__ float bf2f(unsigned short h) {
    return __uint_as_float(((unsigned)h) << 16);
}

// ---------------------------------------------------------------------------
// Kernel 1: L2-normalize + bf16-round + compact. 512 blocks x 256 threads,
// 16 rows per block. Thread 0 claims a slot range with ONE atomicAdd pair
// (16x fewer serialized RMWs than one-per-row). Anchors (domain==0) fill
// [0,nA) ascending; fields fill from the back. sqG[slot] = sum of squares of
// the bf16-ROUNDED row so d^2 = |a|^2+|f|^2-2ab is self-consistent with the
// MFMA dot products.
// ---------------------------------------------------------------------------
__global__ __launch_bounds__(256) void normalize_compact(
    const float* __restrict__ feat, const int* __restrict__ labels,
    const int* __restrict__ dom, unsigned short* __restrict__ G,
    int* __restrict__ labG, float* __restrict__ sqG, unsigned* __restrict__ cnt)
{
    const int r0 = blockIdx.x * 16;
    const int t = threadIdx.x;
    const int lane = t & 63, w = t >> 6;
    __shared__ float sbufA[4], sbufB[4];
    __shared__ int slot_s[16];

    if (t == 0) {
        int isA[16]; int a = 0;
        #pragma unroll
        for (int i = 0; i < 16; ++i) { isA[i] = (dom[r0 + i] == 0) ? 1 : 0; a += isA[i]; }
        const int baseA = (int)atomicAdd(&cnt[0], (unsigned)a);
        const int baseF = (int)atomicAdd(&cnt[1], (unsigned)(16 - a));
        int ai = 0, fi = 0;
        #pragma unroll
        for (int i = 0; i < 16; ++i) {
            const int slot = isA[i] ? (baseA + ai++) : (B_ROWS - 1 - (baseF + fi++));
            slot_s[i] = slot;
            labG[slot] = labels[r0 + i];
        }
    }
    __syncthreads();

    for (int i = 0; i < 16; ++i) {
        const int row = r0 + i;
        const float4 v = ((const float4*)(feat + (size_t)row * DIM))[t];
        float ss = v.x * v.x + v.y * v.y + v.z * v.z + v.w * v.w;
        #pragma unroll
        for (int s = 32; s > 0; s >>= 1) ss += __shfl_down(ss, s);
        if (lane == 0) sbufA[w] = ss;
        __syncthreads();
        const float total = sbufA[0] + sbufA[1] + sbufA[2] + sbufA[3];
        const float inv = 1.0f / fmaxf(sqrtf(total), 1e-12f);

        float fv[4] = {v.x * inv, v.y * inv, v.z * inv, v.w * inv};
        unsigned short ub[4];
        float ss2 = 0.0f;
        #pragma unroll
        for (int j = 0; j < 4; ++j) {
            ub[j] = f2bf_rne(fv[j]);
            const float fr = bf2f(ub[j]);
            ss2 += fr * fr;
        }
        #pragma unroll
        for (int s = 32; s > 0; s >>= 1) ss2 += __shfl_down(ss2, s);
        if (lane == 0) sbufB[w] = ss2;
        __syncthreads();

        const int slot = slot_s[i];
        if (t == 0) sqG[slot] = sbufB[0] + sbufB[1] + sbufB[2] + sbufB[3];
        ushort4 pk; pk.x = ub[0]; pk.y = ub[1]; pk.z = ub[2]; pk.w = ub[3];
        ((ushort4*)(G + (size_t)slot * DIM))[t] = pk;
    }
}

// ---------------------------------------------------------------------------
// Kernel 2 (THE EXPERIMENT): persistent 128x128 tiles, 4 waves per block,
// each wave a 64x64 sub-tile (4x4 of 16x16x32 bf16 MFMA). A/B fragments are
// loaded straight from global: lane l15 reads row (..+l15), 16 B at k-offset
// quad*16 — 16 fully-used 64 B sectors per load instruction. No LDS, no
// __syncthreads in the K-loop. Waves sharing a row strip hit L1/L2.
// Epilogue: min d^2 per anchor row -> atomicMin (uint order, d^2 >= 0).
// ---------------------------------------------------------------------------
__global__ __launch_bounds__(256) void tile_mindist(
    const unsigned short* __restrict__ G, const int* __restrict__ labG,
    const float* __restrict__ sqG, const unsigned* __restrict__ cnt,
    unsigned* __restrict__ posmin, unsigned* __restrict__ negmin)
{
    const int nA = (int)cnt[0];
    const int nF = B_ROWS - nA;
    const int nTA = (nA + 127) >> 7;
    const int nTF = (nF + 127) >> 7;
    const int total = nTA * nTF;

    const int t = threadIdx.x;
    const int lane = t & 63, w = t >> 6;
    const int wm = w >> 1, wn = w & 1;          // wave sub-tile coords (x64)
    const int l15 = lane & 15, quad = lane >> 4;
    const char* Gb = (const char*)G;

    for (int tile = blockIdx.x; tile < total; tile += gridDim.x) {
        const int tx = tile % nTA;
        const int ty = tile / nTA;
        const int rowA0 = tx * 128;
        const int rowF0 = nA + ty * 128;

        const char* pA[4]; const char* pF[4];
        #pragma unroll
        for (int f = 0; f < 4; ++f) {
            const int rA = rowA0 + wm * 64 + f * 16 + l15;   // <= 8191 always
            int rF = rowF0 + wn * 64 + f * 16 + l15;
            if (rF > B_ROWS - 1) rF = B_ROWS - 1;            // clamp; masked later
            pA[f] = Gb + (size_t)rA * (DIM * 2) + quad * 16;
            pF[f] = Gb + (size_t)rF * (DIM * 2) + quad * 16;
        }

        f32x4 acc[4][4] = {};

        for (int kb = 0; kb < DIM * 2; kb += 256) {   // 8 outer iters
            #pragma unroll
            for (int u = 0; u < 4; ++u) {             // 4 K-steps of 64 B
                const int off = kb + u * 64;
                bf16x8 a[4], b[4];
                #pragma unroll
                for (int fm = 0; fm < 4; ++fm) a[fm] = *(const bf16x8*)(pA[fm] + off);
                #pragma unroll
                for (int fn = 0; fn < 4; ++fn) b[fn] = *(const bf16x8*)(pF[fn] + off);
                #pragma unroll
                for (int fm = 0; fm < 4; ++fm)
                    #pragma unroll
                    for (int fn = 0; fn < 4; ++fn)
                        acc[fm][fn] = __builtin_amdgcn_mfma_f32_16x16x32_bf16(
                            a[fm], b[fn], acc[fm][fn], 0, 0, 0);
            }
        }

        // Epilogue. C/D layout: col = lane&15 (field), row = quad*4+reg (anchor).
        const float INFV = __uint_as_float(0x7f800000u);
        float sqf[4]; int lf_[4]; bool vf[4];
        #pragma unroll
        for (int fn = 0; fn < 4; ++fn) {
            const int rf = rowF0 + wn * 64 + fn * 16 + l15;
            vf[fn] = rf < B_ROWS;
            const int rc = vf[fn] ? rf : (B_ROWS - 1);
            sqf[fn] = sqG[rc];
            lf_[fn] = labG[rc];
        }
        #pragma unroll
        for (int fm = 0; fm < 4; ++fm) {
            #pragma unroll
            for (int r = 0; r < 4; ++r) {
                const int ra = rowA0 + wm * 64 + fm * 16 + quad * 4 + r;
                const bool va = ra < nA;
                const int rac = va ? ra : 0;
                const float sqa = sqG[rac];
                const int la_ = labG[rac];
                float pmin = INFV, nmin = INFV;
                #pragma unroll
                for (int fn = 0; fn < 4; ++fn) {
                    const float dd = fmaxf(sqa + sqf[fn] - 2.0f * acc[fm][fn][r], 0.0f);
                    if (vf[fn]) {
                        if (la_ == lf_[fn]) pmin = fminf(pmin, dd);
                        else                nmin = fminf(nmin, dd);
                    }
                }
                #pragma unroll
                for (int s = 1; s < 16; s <<= 1) {
                    pmin = fminf(pmin, __shfl_xor(pmin, s));
                    nmin = fminf(nmin, __shfl_xor(nmin, s));
                }
                if (l15 == 0 && va) {
                    if (pmin < INFV) atomicMin(&posmin[ra], __float_as_uint(pmin));
                    if (nmin < INFV) atomicMin(&negmin[ra], __float_as_uint(nmin));
                }
            }
        }
    }
}

// ---------------------------------------------------------------------------
// Kernel 3: sqrt(d^2 mins) + hinge + sum/count. Untouched slots stay
// 0xFFFFFFFF and drop out as invalid.
// ---------------------------------------------------------------------------
__global__ __launch_bounds__(256) void reduce_loss(
    const unsigned* __restrict__ posmin, const unsigned* __restrict__ negmin,
    float* __restrict__ accum)
{
    const int i = blockIdx.x * 256 + threadIdx.x;
    const unsigned up = posmin[i], un = negmin[i];
    float tl = 0.0f, c = 0.0f;
    if (up != 0xFFFFFFFFu && un != 0xFFFFFFFFu) {
        const float pd = sqrtf(__uint_as_float(up));
        const float nd = sqrtf(__uint_as_float(un));
        tl = fmaxf(pd - nd + 0.3f, 0.0f);
        c = 1.0f;
    }
    #pragma unroll
    for (int s = 32; s > 0; s >>= 1) {
        tl += __shfl_down(tl, s);
        c  += __shfl_down(c, s);
    }
    __shared__ float sb[8];
    const int lane = threadIdx.x & 63, w = threadIdx.x >> 6;
    if (lane == 0) { sb[w] = tl; sb[4 + w] = c; }
    __syncthreads();
    if (threadIdx.x == 0) {
        atomicAdd(&accum[0], sb[0] + sb[1] + sb[2] + sb[3]);
        atomicAdd(&accum[1], sb[4] + sb[5] + sb[6] + sb[7]);
    }
}

__global__ void finalize(const float* __restrict__ accum, float* __restrict__ out) {
    const float s = accum[0], c = accum[1];
    out[0] = (c > 0.0f) ? s / fmaxf(c, 1.0f) : 0.0f;
}

// ---------------------------------------------------------------------------
extern "C" void kernel_launch(void* const* d_in, const int* in_sizes, int n_in,
                              void* d_out, int out_size, void* d_ws, size_t ws_size,
                              hipStream_t stream) {
    const float* feat  = (const float*)d_in[0];
    const int* labels  = (const int*)d_in[1];
    const int* dom     = (const int*)d_in[2];
    float* out = (float*)d_out;

    char* ws = (char*)d_ws;
    // Workspace layout (bytes) — identical to validated R4 layout:
    unsigned short* G   = (unsigned short*)(ws);                 // 16,777,216
    int*      labG      = (int*)(ws + 16777216);                 //     32,768
    float*    sqG       = (float*)(ws + 16809984);               //     32,768
    unsigned* posmin    = (unsigned*)(ws + 16842752);            //     32,768
    unsigned* negmin    = (unsigned*)(ws + 16875520);            //     32,768
    unsigned* cnt       = (unsigned*)(ws + 16908288);            //  8 (cntA, cntF)
    float*    accum     = (float*)(ws + 16908296);               //  8 (sum, count)

    hipMemsetAsync(posmin, 0xFF, 65536, stream);   // posmin+negmin contiguous
    hipMemsetAsync(cnt, 0, 16, stream);            // counters + accum

    normalize_compact<<<512, 256, 0, stream>>>(feat, labels, dom, G, labG,
                                               sqG, cnt);

    // Max tiles over all nA splits: ceil(a/128)*ceil((8192-a)/128) <= 1056.
    tile_mindist<<<1056, 256, 0, stream>>>(G, labG, sqG, cnt, posmin, negmin);

    reduce_loss<<<B_ROWS / 256, 256, 0, stream>>>(posmin, negmin, accum);
    finalize<<<1, 1, 0, stream>>>(accum, out);
}

// Round 8
// 188.230 us; speedup vs baseline: 1.4824x; 1.4824x over previous
//
#include <hip/hip_runtime.h>

// ---------------------------------------------------------------------------
// TripletContrastiveLoss on MI355X (gfx950)  — Round 8
// Tile: reverted verbatim to R4's measured-best LDS double-buffered pipeline
//       (103 µs; R7's LDS-free variant was latency-bound at 178 µs).
// Experiment: zero-atomic slot assignment (1-block LDS prefix scan) +
//       one-row-per-WAVE normalize (no barriers, no atomics) — attacks the
//       ~100-166 µs non-tile overhead traced to same-line atomic chains and
//       R7's serial 16-row loop.
// Hard rules from the failure pattern: ws footprint <= 16,908,304 B
// (slotOf overlays posmin, consumed before its memset), 256-thread blocks
// only, no global_load_lds.
// ---------------------------------------------------------------------------

#define B_ROWS 8192
#define DIM    1024

typedef __bf16 bf16x8 __attribute__((ext_vector_type(8)));
typedef float  f32x4  __attribute__((ext_vector_type(4)));

__device__ __forceinline__ unsigned short f2bf_rne(float x) {
    unsigned u = __float_as_uint(x);
    unsigned r = (u + 0x7FFFu + ((u >> 16) & 1u)) >> 16;
    return (unsigned short)r;
}
__device__ __forceinline__ float bf2f(unsigned short h) {
    return __uint_as_float(((unsigned)h) << 16);
}

// ---------------------------------------------------------------------------
// Kernel 0: slot assignment via LDS prefix scan. 1 block x 256 threads,
// 32 rows/thread (anchor flags packed in a 32-bit mask). Zero atomics.
// slot(row) = #anchors before row (anchors ascend from 0); fields get
// nA + #fields-before (order within partitions is irrelevant — downstream is
// min-reductions). Writes cnt[0] = nA.
// ---------------------------------------------------------------------------
__global__ __launch_bounds__(256) void compute_slots(
    const int* __restrict__ dom, int* __restrict__ slotOf,
    unsigned* __restrict__ cnt)
{
    __shared__ int cnts[256];
    __shared__ int base[257];
    const int t = threadIdx.x;
    const int p0 = t * 32;

    unsigned mask = 0u; int c = 0;
    #pragma unroll
    for (int i = 0; i < 32; ++i) {
        const int isA = (dom[p0 + i] == 0) ? 1 : 0;
        mask |= ((unsigned)isA) << i;
        c += isA;
    }
    cnts[t] = c;
    __syncthreads();
    if (t == 0) {
        int acc = 0;
        for (int i = 0; i < 256; ++i) { base[i] = acc; acc += cnts[i]; }
        base[256] = acc;
        cnt[0] = (unsigned)acc;                  // nA
    }
    __syncthreads();
    const int nA = base[256];
    int aB = base[t];                            // anchors before row p0
    #pragma unroll
    for (int i = 0; i < 32; ++i) {
        const int isA = (mask >> i) & 1;
        slotOf[p0 + i] = isA ? aB : nA + (p0 + i - aB);
        aB += isA;
    }
}

// ---------------------------------------------------------------------------
// Kernel 1: one row per WAVE. 2048 blocks x 256 threads (4 waves). Wave-local
// shuffle reductions only — no __syncthreads, no atomics. L2-normalize in
// fp32, round to bf16, scatter to slotOf[row]. sqG[slot] = sum of squares of
// the bf16-ROUNDED row (self-consistent with MFMA dots).
// ---------------------------------------------------------------------------
__global__ __launch_bounds__(256) void normalize_rows(
    const float* __restrict__ feat, const int* __restrict__ labels,
    const int* __restrict__ slotOf, unsigned short* __restrict__ G,
    int* __restrict__ labG, float* __restrict__ sqG)
{
    const int wv = threadIdx.x >> 6, lane = threadIdx.x & 63;
    const int row = blockIdx.x * 4 + wv;

    const float4* src = (const float4*)(feat + (size_t)row * DIM);
    float4 v[4];
    float ss = 0.0f;
    #pragma unroll
    for (int j = 0; j < 4; ++j) {
        v[j] = src[j * 64 + lane];
        ss += v[j].x * v[j].x + v[j].y * v[j].y + v[j].z * v[j].z + v[j].w * v[j].w;
    }
    #pragma unroll
    for (int s = 32; s > 0; s >>= 1) ss += __shfl_xor(ss, s);   // all lanes
    const float inv = 1.0f / fmaxf(sqrtf(ss), 1e-12f);

    const int slot = slotOf[row];
    unsigned short ub[16];
    float ss2 = 0.0f;
    #pragma unroll
    for (int j = 0; j < 4; ++j) {
        const float f0 = v[j].x * inv, f1 = v[j].y * inv,
                    f2 = v[j].z * inv, f3 = v[j].w * inv;
        ub[j * 4 + 0] = f2bf_rne(f0); ub[j * 4 + 1] = f2bf_rne(f1);
        ub[j * 4 + 2] = f2bf_rne(f2); ub[j * 4 + 3] = f2bf_rne(f3);
        #pragma unroll
        for (int q = 0; q < 4; ++q) {
            const float fr = bf2f(ub[j * 4 + q]);
            ss2 += fr * fr;
        }
    }
    #pragma unroll
    for (int s = 32; s > 0; s >>= 1) ss2 += __shfl_xor(ss2, s);
    if (lane == 0) {
        sqG[slot]  = ss2;
        labG[slot] = labels[row];
    }
    ushort4* dst = (ushort4*)(G + (size_t)slot * DIM);
    #pragma unroll
    for (int j = 0; j < 4; ++j) {
        ushort4 pk;
        pk.x = ub[j * 4 + 0]; pk.y = ub[j * 4 + 1];
        pk.z = ub[j * 4 + 2]; pk.w = ub[j * 4 + 3];
        dst[j * 64 + lane] = pk;
    }
}

// ---------------------------------------------------------------------------
// Kernel 2 (verbatim R4, measured 103 µs): persistent 128x128 tiles, 4 waves
// (each 64x64 via 4x4 of 16x16x32 bf16 MFMA), K=1024 in 32 steps. Double-
// buffered LDS (stride 40 shorts), VGPR prefetch of step k+1 before the
// MFMAs of step k, ONE barrier per step. Epilogue: min d^2 per anchor row ->
// atomicMin (uint order, d^2 >= 0).
// ---------------------------------------------------------------------------
__global__ __launch_bounds__(256) void tile_mindist(
    const unsigned short* __restrict__ G, const int* __restrict__ labG,
    const float* __restrict__ sqG, const unsigned* __restrict__ cnt,
    unsigned* __restrict__ posmin, unsigned* __restrict__ negmin)
{
    const int nA = (int)cnt[0];
    const int nF = B_ROWS - nA;
    const int nTA = (nA + 127) >> 7;
    const int nTF = (nF + 127) >> 7;
    const int total = nTA * nTF;

    // [buf][A=0/F=1][128 rows x 40 shorts]  = 40,960 B
    __shared__ __align__(16) unsigned short S[2][2][128 * 40];

    const int t = threadIdx.x;
    const int lane = t & 63, w = t >> 6;
    const int wm = w >> 1, wn = w & 1;          // wave sub-tile coords (x64)
    const int l15 = lane & 15, quad = lane >> 4;

    // Staging geometry: thread q (and q+256) fills row q>>2, 16-B chunk q&3.
    const int r0 = t >> 2;                       // rows r0 and r0+64
    const int cByte = (t & 3) * 16;              // byte col within 64-B K-chunk
    const int wOff0 = r0 * 40 + (cByte >> 1);    // LDS write offset (shorts)
    const int wOff1 = (r0 + 64) * 40 + (cByte >> 1);
    // Fragment read offsets (shorts)
    const int rdA = (wm * 64 + l15) * 40 + quad * 8;
    const int rdF = (wn * 64 + l15) * 40 + quad * 8;

    const char* Gb = (const char*)G;

    for (int tile = blockIdx.x; tile < total; tile += gridDim.x) {
        const int tx = tile % nTA;
        const int ty = tile / nTA;
        const int rowA0 = tx * 128;
        const int rowF0 = nA + ty * 128;

        int rF0c = rowF0 + r0;       if (rF0c > B_ROWS - 1) rF0c = B_ROWS - 1;
        int rF1c = rowF0 + r0 + 64;  if (rF1c > B_ROWS - 1) rF1c = B_ROWS - 1;
        const char* gA0 = Gb + (size_t)(rowA0 + r0) * (DIM * 2) + cByte;
        const char* gA1 = gA0 + (size_t)64 * (DIM * 2);
        const char* gF0 = Gb + (size_t)rF0c * (DIM * 2) + cByte;
        const char* gF1 = Gb + (size_t)rF1c * (DIM * 2) + cByte;

        f32x4 acc[4][4] = {};

        // Prologue: stage K-chunk 0 into buffer 0.
        {
            const uint4 a0 = *(const uint4*)(gA0);
            const uint4 a1 = *(const uint4*)(gA1);
            const uint4 f0 = *(const uint4*)(gF0);
            const uint4 f1 = *(const uint4*)(gF1);
            *(uint4*)&S[0][0][wOff0] = a0;
            *(uint4*)&S[0][0][wOff1] = a1;
            *(uint4*)&S[0][1][wOff0] = f0;
            *(uint4*)&S[0][1][wOff1] = f1;
        }
        __syncthreads();

        #pragma unroll 4
        for (int step = 0; step < 32; ++step) {
            const int cur = step & 1;
            const bool has_next = step < 31;
            uint4 na0, na1, nf0, nf1;
            if (has_next) {                       // prefetch K-chunk step+1
                const int off = (step + 1) * 64;
                na0 = *(const uint4*)(gA0 + off);
                na1 = *(const uint4*)(gA1 + off);
                nf0 = *(const uint4*)(gF0 + off);
                nf1 = *(const uint4*)(gF1 + off);
            }

            const unsigned short* pa = &S[cur][0][rdA];
            const unsigned short* pf = &S[cur][1][rdF];
            bf16x8 a[4], b[4];
            #pragma unroll
            for (int fm = 0; fm < 4; ++fm) a[fm] = *(const bf16x8*)(pa + fm * 640);
            #pragma unroll
            for (int fn = 0; fn < 4; ++fn) b[fn] = *(const bf16x8*)(pf + fn * 640);
            #pragma unroll
            for (int fm = 0; fm < 4; ++fm)
                #pragma unroll
                for (int fn = 0; fn < 4; ++fn)
                    acc[fm][fn] = __builtin_amdgcn_mfma_f32_16x16x32_bf16(
                        a[fm], b[fn], acc[fm][fn], 0, 0, 0);

            if (has_next) {                       // stage into the other buffer
                const int nb = cur ^ 1;
                *(uint4*)&S[nb][0][wOff0] = na0;
                *(uint4*)&S[nb][0][wOff1] = na1;
                *(uint4*)&S[nb][1][wOff0] = nf0;
                *(uint4*)&S[nb][1][wOff1] = nf1;
            }
            __syncthreads();                      // one barrier per step
        }

        // Epilogue. C/D layout: col = lane&15 (field), row = quad*4+reg (anchor).
        const float INFV = __uint_as_float(0x7f800000u);
        float sqf[4]; int lf_[4]; bool vf[4];
        #pragma unroll
        for (int fn = 0; fn < 4; ++fn) {
            const int rf = rowF0 + wn * 64 + fn * 16 + l15;
            vf[fn] = rf < B_ROWS;
            const int rc = vf[fn] ? rf : (B_ROWS - 1);
            sqf[fn] = sqG[rc];
            lf_[fn] = labG[rc];
        }
        #pragma unroll
        for (int fm = 0; fm < 4; ++fm) {
            #pragma unroll
            for (int r = 0; r < 4; ++r) {
                const int ra = rowA0 + wm * 64 + fm * 16 + quad * 4 + r;
                const bool va = ra < nA;
                const int rac = va ? ra : 0;
                const float sqa = sqG[rac];
                const int la_ = labG[rac];
                float pmin = INFV, nmin = INFV;
                #pragma unroll
                for (int fn = 0; fn < 4; ++fn) {
                    const float dd = fmaxf(sqa + sqf[fn] - 2.0f * acc[fm][fn][r], 0.0f);
                    if (vf[fn]) {
                        if (la_ == lf_[fn]) pmin = fminf(pmin, dd);
                        else                nmin = fminf(nmin, dd);
                    }
                }
                #pragma unroll
                for (int s = 1; s < 16; s <<= 1) {
                    pmin = fminf(pmin, __shfl_xor(pmin, s));
                    nmin = fminf(nmin, __shfl_xor(nmin, s));
                }
                if (l15 == 0 && va) {
                    if (pmin < INFV) atomicMin(&posmin[ra], __float_as_uint(pmin));
                    if (nmin < INFV) atomicMin(&negmin[ra], __float_as_uint(nmin));
                }
            }
        }
    }
}

// ---------------------------------------------------------------------------
// Kernel 3: sqrt(d^2 mins) + hinge + sum/count. Untouched slots stay
// 0xFFFFFFFF and drop out as invalid.
// ---------------------------------------------------------------------------
__global__ __launch_bounds__(256) void reduce_loss(
    const unsigned* __restrict__ posmin, const unsigned* __restrict__ negmin,
    float* __restrict__ accum)
{
    const int i = blockIdx.x * 256 + threadIdx.x;
    const unsigned up = posmin[i], un = negmin[i];
    float tl = 0.0f, c = 0.0f;
    if (up != 0xFFFFFFFFu && un != 0xFFFFFFFFu) {
        const float pd = sqrtf(__uint_as_float(up));
        const float nd = sqrtf(__uint_as_float(un));
        tl = fmaxf(pd - nd + 0.3f, 0.0f);
        c = 1.0f;
    }
    #pragma unroll
    for (int s = 32; s > 0; s >>= 1) {
        tl += __shfl_down(tl, s);
        c  += __shfl_down(c, s);
    }
    __shared__ float sb[8];
    const int lane = threadIdx.x & 63, w = threadIdx.x >> 6;
    if (lane == 0) { sb[w] = tl; sb[4 + w] = c; }
    __syncthreads();
    if (threadIdx.x == 0) {
        atomicAdd(&accum[0], sb[0] + sb[1] + sb[2] + sb[3]);
        atomicAdd(&accum[1], sb[4] + sb[5] + sb[6] + sb[7]);
    }
}

__global__ void finalize(const float* __restrict__ accum, float* __restrict__ out) {
    const float s = accum[0], c = accum[1];
    out[0] = (c > 0.0f) ? s / fmaxf(c, 1.0f) : 0.0f;
}

// ---------------------------------------------------------------------------
extern "C" void kernel_launch(void* const* d_in, const int* in_sizes, int n_in,
                              void* d_out, int out_size, void* d_ws, size_t ws_size,
                              hipStream_t stream) {
    const float* feat  = (const float*)d_in[0];
    const int* labels  = (const int*)d_in[1];
    const int* dom     = (const int*)d_in[2];
    float* out = (float*)d_out;

    char* ws = (char*)d_ws;
    // Workspace layout (bytes) — identical footprint to validated R4 layout:
    unsigned short* G   = (unsigned short*)(ws);                 // 16,777,216
    int*      labG      = (int*)(ws + 16777216);                 //     32,768
    float*    sqG       = (float*)(ws + 16809984);               //     32,768
    unsigned* posmin    = (unsigned*)(ws + 16842752);            //     32,768
    unsigned* negmin    = (unsigned*)(ws + 16875520);            //     32,768
    unsigned* cnt       = (unsigned*)(ws + 16908288);            //  8 (nA, unused)
    float*    accum     = (float*)(ws + 16908296);               //  8 (sum, count)
    // slotOf OVERLAYS posmin: written by compute_slots, consumed by
    // normalize_rows, then clobbered by the 0xFF memset (stream-ordered).
    int*      slotOf    = (int*)(ws + 16842752);

    hipMemsetAsync(cnt, 0, 16, stream);             // cnt + accum = 0

    compute_slots<<<1, 256, 0, stream>>>(dom, slotOf, cnt);
    normalize_rows<<<B_ROWS / 4, 256, 0, stream>>>(feat, labels, slotOf,
                                                   G, labG, sqG);

    hipMemsetAsync(posmin, 0xFF, 65536, stream);    // posmin+negmin = +inf bits

    // Max tiles over all nA splits: ceil(a/128)*ceil((8192-a)/128) <= 1056.
    tile_mindist<<<1056, 256, 0, stream>>>(G, labG, sqG, cnt, posmin, negmin);

    reduce_loss<<<B_ROWS / 256, 256, 0, stream>>>(posmin, negmin, accum);
    finalize<<<1, 1, 0, stream>>>(accum, out);
}